// Round 9
// baseline (978.986 us; speedup 1.0000x reference)
//
#include <hip/hip_runtime.h>
#include <cstdint>
#include <cstddef>

#define HD 4096
#define EE 8
#define LL 8
#define RR 4
#define VV 32000
#define NTOK 2048
#define NKT (HD / 64)   // 64 K-tiles of BK=64
#define T8 8            // tokens per layer block

typedef __attribute__((ext_vector_type(8))) short bf16x8;
typedef __attribute__((ext_vector_type(4))) float f32x4;
typedef __attribute__((ext_vector_type(4))) unsigned short u16x4;

static __device__ __forceinline__ unsigned short f2bf(float f) {
    unsigned int u = __builtin_bit_cast(unsigned int, f);
    unsigned int r = (u + 0x7FFFu + ((u >> 16) & 1u)) >> 16;
    return (unsigned short)r;
}

// ---------------------------------------------------------------------------
// Kernel 1: router (double softmax) + 8 fused LoRA layers. (unchanged R8)
// 256 blocks x 1024 threads (16 waves, 4/SIMD); 8 tokens/block; runs ALONE.
// ---------------------------------------------------------------------------
__global__ __launch_bounds__(1024, 4) void fused_layers(
    const float* __restrict__ h_in,
    const float* __restrict__ router_w,
    const float* __restrict__ router_b,
    const float* __restrict__ expert_B,   // [E][L][R][H]
    const float* __restrict__ expert_A,   // [E][L][H][R]
    const float* __restrict__ deep_B,     // [L][R][H]
    const float* __restrict__ deep_A,     // [L][H][R]
    float* __restrict__ router_logits,
    unsigned short* __restrict__ h_out)
{
    __shared__ float h_lds[T8][HD];       // 128 KB
    __shared__ float zw_lds[T8][32];
    __shared__ float probs_lds[T8][EE];
    __shared__ float psum_lds[T8];
    __shared__ float red[16][T8][4];
    __shared__ float low_lds[T8][4];

    const int tid  = threadIdx.x;
    const int lane = tid & 63;
    const int wv   = tid >> 6;            // 0..15
    const int t0   = blockIdx.x * T8;

    for (int t = 0; t < T8; ++t)
        ((float4*)h_lds[t])[tid] = ((const float4*)(h_in + (size_t)(t0 + t) * HD))[tid];
    __syncthreads();

    if (wv < T8) {
        float racc[EE];
        #pragma unroll
        for (int e = 0; e < EE; ++e) racc[e] = 0.f;
        const float4* h4 = (const float4*)h_lds[wv];
        for (int k4 = 0; k4 < HD / 256; ++k4) {
            int idx = lane + k4 * 64;
            float4 hv = h4[idx];
            #pragma unroll
            for (int e = 0; e < EE; ++e) {
                float4 w4 = ((const float4*)(router_w + e * HD))[idx];
                racc[e] += w4.x * hv.x + w4.y * hv.y + w4.z * hv.z + w4.w * hv.w;
            }
        }
        #pragma unroll
        for (int e = 0; e < EE; ++e)
            for (int m = 1; m < 64; m <<= 1) racc[e] += __shfl_xor(racc[e], m);
        if (lane == 0) {
            float lg[EE], mx = -1e30f;
            #pragma unroll
            for (int e = 0; e < EE; ++e) { lg[e] = racc[e] + router_b[e]; mx = fmaxf(mx, lg[e]); }
            float s = 0.f;
            #pragma unroll
            for (int e = 0; e < EE; ++e) { lg[e] = expf(lg[e] - mx); s += lg[e]; }
            float inv = 1.f / s;
            float p1[EE], mx2 = -1e30f;
            #pragma unroll
            for (int e = 0; e < EE; ++e) { p1[e] = lg[e] * inv; mx2 = fmaxf(mx2, p1[e]); }
            float s2 = 0.f, q2[EE];
            #pragma unroll
            for (int e = 0; e < EE; ++e) { q2[e] = expf(p1[e] - mx2); s2 += q2[e]; }
            float inv2 = 1.f / s2, ps = 0.f;
            #pragma unroll
            for (int e = 0; e < EE; ++e) {
                float p2 = q2[e] * inv2;
                probs_lds[wv][e] = p2;
                ps += p2;
                router_logits[(size_t)(t0 + wv) * EE + e] = p1[e];
            }
            psum_lds[wv] = ps;
        }
    }
    __syncthreads();

    for (int li = 0; li < LL; ++li) {
        {
            float zacc[2][T8] = {};
            const float4* bp4[2];
            #pragma unroll
            for (int j = 0; j < 2; ++j) {
                int er = wv * 2 + j;
                int e = er >> 2, r = er & 3;
                bp4[j] = (const float4*)(expert_B + (size_t)((e * LL + li) * RR + r) * HD);
            }
            for (int k4 = 0; k4 < HD / 256; ++k4) {
                int idx = lane + k4 * 64;
                float4 hv[T8];
                #pragma unroll
                for (int t = 0; t < T8; ++t) hv[t] = ((const float4*)h_lds[t])[idx];
                #pragma unroll
                for (int j = 0; j < 2; ++j) {
                    float4 w4 = bp4[j][idx];
                    #pragma unroll
                    for (int t = 0; t < T8; ++t)
                        zacc[j][t] += w4.x * hv[t].x + w4.y * hv[t].y +
                                      w4.z * hv[t].z + w4.w * hv[t].w;
                }
            }
            #pragma unroll
            for (int j = 0; j < 2; ++j)
                #pragma unroll
                for (int t = 0; t < T8; ++t) {
                    float v = zacc[j][t];
                    for (int m = 1; m < 64; m <<= 1) v += __shfl_xor(v, m);
                    zacc[j][t] = v;
                }
            if (lane == 0) {
                #pragma unroll
                for (int j = 0; j < 2; ++j) {
                    int er = wv * 2 + j;
                    #pragma unroll
                    for (int t = 0; t < T8; ++t)
                        zw_lds[t][er] = zacc[j][t] * probs_lds[t][er >> 2];
                }
            }
        }
        __syncthreads();

        float dacc[T8][4] = {};
        const int pbase = wv * 256 + lane;
        for (int e = 0; e < EE; ++e) {
            float zwt[T8][4];
            #pragma unroll
            for (int t = 0; t < T8; ++t)
                #pragma unroll
                for (int r = 0; r < RR; ++r) zwt[t][r] = zw_lds[t][e * 4 + r];
            const float4* ap = (const float4*)expert_A + (size_t)(e * LL + li) * HD;
            #pragma unroll
            for (int it = 0; it < 4; ++it) {
                float4 a4 = ap[pbase + it * 64];
                #pragma unroll
                for (int t = 0; t < T8; ++t)
                    dacc[t][it] += zwt[t][0] * a4.x + zwt[t][1] * a4.y +
                                   zwt[t][2] * a4.z + zwt[t][3] * a4.w;
            }
        }

        float lowacc[T8][4] = {};
        float psv[T8];
        #pragma unroll
        for (int t = 0; t < T8; ++t) psv[t] = psum_lds[t];
        const float* dbp = deep_B + (size_t)li * (RR * HD);
        #pragma unroll
        for (int it = 0; it < 4; ++it) {
            int pos = pbase + it * 64;
            float db0 = dbp[pos], db1 = dbp[HD + pos], db2 = dbp[2 * HD + pos], db3 = dbp[3 * HD + pos];
            #pragma unroll
            for (int t = 0; t < T8; ++t) {
                float c = h_lds[t][pos] * psv[t] + dacc[t][it];
                h_lds[t][pos] = c;
                lowacc[t][0] += c * db0; lowacc[t][1] += c * db1;
                lowacc[t][2] += c * db2; lowacc[t][3] += c * db3;
            }
        }
        #pragma unroll
        for (int t = 0; t < T8; ++t)
            #pragma unroll
            for (int r = 0; r < RR; ++r) {
                float v = lowacc[t][r];
                for (int m = 1; m < 64; m <<= 1) v += __shfl_xor(v, m);
                lowacc[t][r] = v;
            }
        if (lane == 0) {
            #pragma unroll
            for (int t = 0; t < T8; ++t)
                #pragma unroll
                for (int r = 0; r < RR; ++r) red[wv][t][r] = lowacc[t][r];
        }
        __syncthreads();
        if (tid < 32) {
            int t = tid >> 2, r = tid & 3;
            float s = 0.f;
            #pragma unroll
            for (int w = 0; w < 16; ++w) s += red[w][t][r];
            low_lds[t][r] = s;
        }
        __syncthreads();

        {
            float lw[T8][4];
            #pragma unroll
            for (int t = 0; t < T8; ++t)
                #pragma unroll
                for (int r = 0; r < RR; ++r) lw[t][r] = low_lds[t][r];
            const float4* dap = (const float4*)deep_A + (size_t)li * HD;
            #pragma unroll
            for (int it = 0; it < 4; ++it) {
                int pos = pbase + it * 64;
                float4 a4 = dap[pos];
                #pragma unroll
                for (int t = 0; t < T8; ++t)
                    h_lds[t][pos] += lw[t][0] * a4.x + lw[t][1] * a4.y +
                                     lw[t][2] * a4.z + lw[t][3] * a4.w;
            }
        }
        __syncthreads();
    }

    for (int t = 0; t < T8; ++t) {
        float4 v = ((const float4*)h_lds[t])[tid];
        ushort4 o;
        o.x = f2bf(v.x); o.y = f2bf(v.y); o.z = f2bf(v.z); o.w = f2bf(v.w);
        ((ushort4*)(h_out + (size_t)(t0 + t) * HD))[tid] = o;
    }
}

// ---------------------------------------------------------------------------
// Kernel 2: lm_head_w fp32 -> bf16, nontemporal. (unchanged R8)
// ---------------------------------------------------------------------------
__global__ __launch_bounds__(256) void cvt_kernel(const f32x4* __restrict__ in,
                                                  u16x4* __restrict__ out, int n4)
{
    int i = blockIdx.x * 256 + threadIdx.x;
    int stride = gridDim.x * 256;
    for (; i < n4; i += stride) {
        f32x4 v = __builtin_nontemporal_load(&in[i]);
        u16x4 o;
        o.x = f2bf(v.x); o.y = f2bf(v.y); o.z = f2bf(v.z); o.w = f2bf(v.w);
        __builtin_nontemporal_store(o, &out[i]);
    }
}

// ---------------------------------------------------------------------------
// Kernel 3: 256x256 8-phase bf16 GEMM — DEEP-PREFETCH schedule.
//
// Slot lifetimes within iter kt (reads buf[cur=kt&1]):
//   B[cur] LDS dead after P1 (bF0 read P0, bF1 read P1, held in regs after);
//   A[cur] LDS dead after P2 (mh1 read P2, mh0 held in regs from P0).
// Stages (all tile kt+2 -> cur):  P2: B-h0.  P3: B-h1, A-h0, A-h1.
// vmcnt ledger at kt's P3 gate (queue old->new, 2 loads per stage):
//   [B(kt+1)h0, B(kt+1)h1, A(kt+1)h0, A(kt+1)h1,   <- issued iter kt-1 P2/P3
//    B(kt+2)h0, B(kt+2)h1, A(kt+2)h0, A(kt+2)h1]   <- issued iter kt   P2/P3
//   = 16 outstanding; vmcnt(8) drains tile kt+1 (issued 4-5 phases ~800-1000cy
//   earlier >= HBM latency), leaves tile kt+2's 8 in flight.
// Tail (kt+2 >= NKT, nothing new issued): vmcnt(0).
// Prologue: stage tiles 0 and 1 (16 loads), vmcnt(8) -> tile0 landed.
// ---------------------------------------------------------------------------
#define GLD(src, dst) __builtin_amdgcn_global_load_lds( \
    (const __attribute__((address_space(1))) unsigned int*)(src), \
    (__attribute__((address_space(3))) unsigned int*)(dst), 16, 0, 0)

#define STAGE(pp, matoff, bufv, hh, ktv) do { \
    char* db_ = smem + (bufv) * 65536 + (matoff) + (hh) * 16384 + wv * 1024; \
    GLD(pp[0] + (size_t)(hh) * (128ull * HD * 2) + (size_t)(ktv) * 128, db_); \
    GLD(pp[1] + (size_t)(hh) * (128ull * HD * 2) + (size_t)(ktv) * 128, db_ + 8192); \
} while (0)

#define LDSREAD(off) (*(const bf16x8*)(smem + (off)))

__global__ __launch_bounds__(512, 2) void lm_gemm256(
    const unsigned short* __restrict__ A,
    const unsigned short* __restrict__ Bw,
    float* __restrict__ C)
{
    __shared__ __attribute__((aligned(128))) char smem[131072];

    const int bid = blockIdx.x;
    const int swz = (bid & 7) * 125 + (bid >> 3);
    const int bm = swz & 7;
    const int bn = swz >> 3;

    const int tid  = threadIdx.x;
    const int lane = tid & 63;
    const int wv   = tid >> 6;
    const int wr   = wv >> 2;
    const int wc   = wv & 3;

    const char* pA[2];
    const char* pB[2];
    #pragma unroll
    for (int q = 0; q < 2; ++q) {
        int off = (q * 512 + tid) * 16;
        int p = off ^ (((off >> 9) & 1) << 5);
        int st = p >> 10;
        int r  = (st >> 1) * 16 + ((p >> 6) & 15);
        int cb = (st & 1) * 64 + (p & 63);
        pA[q] = (const char*)(A  + (size_t)(bm * 256 + r) * HD) + cb;
        pB[q] = (const char*)(Bw + (size_t)(bn * 256 + r) * HD) + cb;
    }

    const int xlane = ((lane >> 3) & 1) << 5;
    const int abase = ((wr * 8) << 11) + ((lane & 15) << 6) + ((lane >> 4) << 4);
    const int bbase = 32768 + ((wc * 4) << 11) + ((lane & 15) << 6) + ((lane >> 4) << 4);

    f32x4 acc[8][4] = {};
    bf16x8 aF[4][2], bF0[2][2], bF1[2][2];

    // prologue: tile0 -> buf0, tile1 -> buf1 (A+B each), oldest first
    STAGE(pB, 32768, 0, 0, 0);
    STAGE(pB, 32768, 0, 1, 0);
    STAGE(pA, 0,     0, 0, 0);
    STAGE(pA, 0,     0, 1, 0);
    STAGE(pB, 32768, 1, 0, 1);
    STAGE(pB, 32768, 1, 1, 1);
    STAGE(pA, 0,     1, 0, 1);
    STAGE(pA, 0,     1, 1, 1);
    asm volatile("s_waitcnt vmcnt(8)" ::: "memory");   // tile0 landed; tile1 in flight
    __builtin_amdgcn_s_barrier();
    __builtin_amdgcn_sched_barrier(0);

    #pragma unroll 2
    for (int kt = 0; kt < NKT; ++kt) {
        const int cur = kt & 1;
        const int cb0 = cur << 16;

        // ---------------- PHASE 0 : (mh0, nh0)  [12 ds_reads, no stages]
        #pragma unroll
        for (int i = 0; i < 4; ++i)
            #pragma unroll
            for (int ks = 0; ks < 2; ++ks)
                aF[i][ks] = LDSREAD(cb0 + ((abase + (i << 11) + (ks << 10)) ^ xlane));
        #pragma unroll
        for (int n = 0; n < 2; ++n)
            #pragma unroll
            for (int ks = 0; ks < 2; ++ks)
                bF0[n][ks] = LDSREAD(cb0 + ((bbase + (n << 11) + (ks << 10)) ^ xlane));
        __builtin_amdgcn_s_barrier();
        __builtin_amdgcn_sched_barrier(0);
        __builtin_amdgcn_s_setprio(1);
        #pragma unroll
        for (int ks = 0; ks < 2; ++ks)
            #pragma unroll
            for (int i = 0; i < 4; ++i)
                #pragma unroll
                for (int n = 0; n < 2; ++n)
                    acc[i][n] = __builtin_amdgcn_mfma_f32_16x16x32_bf16(
                        aF[i][ks], bF0[n][ks], acc[i][n], 0, 0, 0);
        __builtin_amdgcn_s_setprio(0);
        __builtin_amdgcn_s_barrier();
        __builtin_amdgcn_sched_barrier(0);

        // ---------------- PHASE 1 : (mh0, nh1)  [4 B reads, no stages]
        #pragma unroll
        for (int n = 0; n < 2; ++n)
            #pragma unroll
            for (int ks = 0; ks < 2; ++ks)
                bF1[n][ks] = LDSREAD(cb0 + ((bbase + ((n + 2) << 11) + (ks << 10)) ^ xlane));
        __builtin_amdgcn_s_barrier();
        __builtin_amdgcn_sched_barrier(0);
        __builtin_amdgcn_s_setprio(1);
        #pragma unroll
        for (int ks = 0; ks < 2; ++ks)
            #pragma unroll
            for (int i = 0; i < 4; ++i)
                #pragma unroll
                for (int n = 0; n < 2; ++n)
                    acc[i][n + 2] = __builtin_amdgcn_mfma_f32_16x16x32_bf16(
                        aF[i][ks], bF1[n][ks], acc[i][n + 2], 0, 0, 0);
        __builtin_amdgcn_s_setprio(0);
        __builtin_amdgcn_s_barrier();
        __builtin_amdgcn_sched_barrier(0);

        // ---------------- PHASE 2 : (mh1, nh1)  [8 A reads + stage B(kt+2)h0]
        #pragma unroll
        for (int i = 0; i < 4; ++i)
            #pragma unroll
            for (int ks = 0; ks < 2; ++ks)
                aF[i][ks] = LDSREAD(cb0 + ((abase + ((i + 4) << 11) + (ks << 10)) ^ xlane));
        if (kt + 2 < NKT) STAGE(pB, 32768, cur, 0, kt + 2);
        __builtin_amdgcn_s_barrier();
        __builtin_amdgcn_sched_barrier(0);
        __builtin_amdgcn_s_setprio(1);
        #pragma unroll
        for (int ks = 0; ks < 2; ++ks)
            #pragma unroll
            for (int i = 0; i < 4; ++i)
                #pragma unroll
                for (int n = 0; n < 2; ++n)
                    acc[i + 4][n + 2] = __builtin_amdgcn_mfma_f32_16x16x32_bf16(
                        aF[i][ks], bF1[n][ks], acc[i + 4][n + 2], 0, 0, 0);
        __builtin_amdgcn_s_setprio(0);
        __builtin_amdgcn_s_barrier();
        __builtin_amdgcn_sched_barrier(0);

        // ---------------- PHASE 3 : (mh1, nh0)  [stage B(kt+2)h1 + A(kt+2)h0/h1; gate]
        if (kt + 2 < NKT) {
            STAGE(pB, 32768, cur, 1, kt + 2);
            STAGE(pA, 0,     cur, 0, kt + 2);
            STAGE(pA, 0,     cur, 1, kt + 2);
            asm volatile("s_waitcnt vmcnt(8)" ::: "memory");  // drain tile kt+1; kt+2 in flight
        } else {
            asm volatile("s_waitcnt vmcnt(0)" ::: "memory");
        }
        __builtin_amdgcn_s_barrier();
        __builtin_amdgcn_sched_barrier(0);
        __builtin_amdgcn_s_setprio(1);
        #pragma unroll
        for (int ks = 0; ks < 2; ++ks)
            #pragma unroll
            for (int i = 0; i < 4; ++i)
                #pragma unroll
                for (int n = 0; n < 2; ++n)
                    acc[i + 4][n] = __builtin_amdgcn_mfma_f32_16x16x32_bf16(
                        aF[i][ks], bF0[n][ks], acc[i + 4][n], 0, 0, 0);
        __builtin_amdgcn_s_setprio(0);
        __builtin_amdgcn_s_barrier();
        __builtin_amdgcn_sched_barrier(0);
    }

    const int crow0 = bm * 256 + wr * 128 + ((lane >> 4) << 2);
    const int ccol0 = bn * 256 + wc * 64 + (lane & 15);
    #pragma unroll
    for (int fm = 0; fm < 8; ++fm)
        #pragma unroll
        for (int fn = 0; fn < 4; ++fn) {
            int row = crow0 + fm * 16;
            int col = ccol0 + fn * 16;
            #pragma unroll
            for (int j = 0; j < 4; ++j)
                C[(size_t)(row + j) * VV + col] = acc[fm][fn][j];
        }
}

// ---------------------------------------------------------------------------
extern "C" void kernel_launch(void* const* d_in, const int* in_sizes, int n_in,
                              void* d_out, int out_size, void* d_ws, size_t ws_size,
                              hipStream_t stream) {
    const float* h_in      = (const float*)d_in[0];
    const float* router_w  = (const float*)d_in[1];
    const float* router_b  = (const float*)d_in[2];
    const float* expert_B  = (const float*)d_in[3];
    const float* expert_A  = (const float*)d_in[4];
    const float* deep_B    = (const float*)d_in[5];
    const float* deep_A    = (const float*)d_in[6];
    const float* lm_head_w = (const float*)d_in[7];

    float* out = (float*)d_out;
    float* router_logits_out = out + (size_t)NTOK * VV;

    unsigned short* h_bf = (unsigned short*)d_ws;
    unsigned short* w_bf = (unsigned short*)((char*)d_ws + (size_t)NTOK * HD * 2);

    fused_layers<<<dim3(NTOK / T8), dim3(1024), 0, stream>>>(
        h_in, router_w, router_b, expert_B, expert_A, deep_B, deep_A,
        router_logits_out, h_bf);

    cvt_kernel<<<dim3(4096), dim3(256), 0, stream>>>(
        (const f32x4*)lm_head_w, (u16x4*)w_bf, VV * HD / 4);

    lm_gemm256<<<dim3((NTOK / 256) * (VV / 256)), dim3(512), 0, stream>>>(
        h_bf, w_bf, out);
}

// Round 10
// 902.756 us; speedup vs baseline: 1.0844x; 1.0844x over previous
//
#include <hip/hip_runtime.h>
#include <cstdint>
#include <cstddef>

#define HD 4096
#define EE 8
#define LL 8
#define RR 4
#define VV 32000
#define NTOK 2048
#define NKT (HD / 64)   // 64 K-tiles of BK=64
#define T8 8            // tokens per layer block
#define N4 (VV * HD / 4)  // 32,768,000 float4 elements in lm_head_w

typedef __attribute__((ext_vector_type(8))) short bf16x8;
typedef __attribute__((ext_vector_type(4))) float f32x4;
typedef __attribute__((ext_vector_type(4))) unsigned short u16x4;

static __device__ __forceinline__ unsigned short f2bf(float f) {
    unsigned int u = __builtin_bit_cast(unsigned int, f);
    unsigned int r = (u + 0x7FFFu + ((u >> 16) & 1u)) >> 16;
    return (unsigned short)r;
}

// ---------------------------------------------------------------------------
// Kernel 1: router + 8 LoRA layers + INLINE lm_head_w cvt (thread-granular).
// 256 blocks x 1024 threads (16 waves). The layer phases are latency-bound
// with idle memory pipes; 4 nontemporal cvt bursts per layer (4x float4 per
// thread each) stream lm_head_w fp32->bf16 "for free" under that latency.
// nt hints keep the stream from evicting the hot ~9 MB expert weights (the
// R3 L2-thrash failure mode). Chunk map: (li,c,block) -> 4096 float4.
// ---------------------------------------------------------------------------
#define CVT_CHUNK(c) do { \
    size_t base_ = ((size_t)(li * 4 + (c)) * 256 + blockIdx.x) * 4096; \
    _Pragma("unroll") \
    for (int q_ = 0; q_ < 4; ++q_) { \
        size_t i_ = base_ + q_ * 1024 + tid; \
        if (i_ < (size_t)N4) { \
            f32x4 v_ = __builtin_nontemporal_load(&lm_w[i_]); \
            u16x4 o_; \
            o_.x = f2bf(v_.x); o_.y = f2bf(v_.y); \
            o_.z = f2bf(v_.z); o_.w = f2bf(v_.w); \
            __builtin_nontemporal_store(o_, &w_bf[i_]); \
        } \
    } \
} while (0)

__global__ __launch_bounds__(1024, 4) void fused_layers_cvt(
    const float* __restrict__ h_in,
    const float* __restrict__ router_w,
    const float* __restrict__ router_b,
    const float* __restrict__ expert_B,   // [E][L][R][H]
    const float* __restrict__ expert_A,   // [E][L][H][R]
    const float* __restrict__ deep_B,     // [L][R][H]
    const float* __restrict__ deep_A,     // [L][H][R]
    float* __restrict__ router_logits,
    unsigned short* __restrict__ h_out,
    const f32x4* __restrict__ lm_w,
    u16x4* __restrict__ w_bf)
{
    __shared__ float h_lds[T8][HD];       // 128 KB
    __shared__ float zw_lds[T8][32];
    __shared__ float probs_lds[T8][EE];
    __shared__ float psum_lds[T8];
    __shared__ float red[16][T8][4];
    __shared__ float low_lds[T8][4];

    const int tid  = threadIdx.x;
    const int lane = tid & 63;
    const int wv   = tid >> 6;            // 0..15
    const int t0   = blockIdx.x * T8;

    for (int t = 0; t < T8; ++t)
        ((float4*)h_lds[t])[tid] = ((const float4*)(h_in + (size_t)(t0 + t) * HD))[tid];
    __syncthreads();

    if (wv < T8) {
        float racc[EE];
        #pragma unroll
        for (int e = 0; e < EE; ++e) racc[e] = 0.f;
        const float4* h4 = (const float4*)h_lds[wv];
        for (int k4 = 0; k4 < HD / 256; ++k4) {
            int idx = lane + k4 * 64;
            float4 hv = h4[idx];
            #pragma unroll
            for (int e = 0; e < EE; ++e) {
                float4 w4 = ((const float4*)(router_w + e * HD))[idx];
                racc[e] += w4.x * hv.x + w4.y * hv.y + w4.z * hv.z + w4.w * hv.w;
            }
        }
        #pragma unroll
        for (int e = 0; e < EE; ++e)
            for (int m = 1; m < 64; m <<= 1) racc[e] += __shfl_xor(racc[e], m);
        if (lane == 0) {
            float lg[EE], mx = -1e30f;
            #pragma unroll
            for (int e = 0; e < EE; ++e) { lg[e] = racc[e] + router_b[e]; mx = fmaxf(mx, lg[e]); }
            float s = 0.f;
            #pragma unroll
            for (int e = 0; e < EE; ++e) { lg[e] = expf(lg[e] - mx); s += lg[e]; }
            float inv = 1.f / s;
            float p1[EE], mx2 = -1e30f;
            #pragma unroll
            for (int e = 0; e < EE; ++e) { p1[e] = lg[e] * inv; mx2 = fmaxf(mx2, p1[e]); }
            float s2 = 0.f, q2[EE];
            #pragma unroll
            for (int e = 0; e < EE; ++e) { q2[e] = expf(p1[e] - mx2); s2 += q2[e]; }
            float inv2 = 1.f / s2, ps = 0.f;
            #pragma unroll
            for (int e = 0; e < EE; ++e) {
                float p2 = q2[e] * inv2;
                probs_lds[wv][e] = p2;
                ps += p2;
                router_logits[(size_t)(t0 + wv) * EE + e] = p1[e];
            }
            psum_lds[wv] = ps;
        }
    }
    __syncthreads();

    for (int li = 0; li < LL; ++li) {
        CVT_CHUNK(0);
        // ---- Z phase: wave wv owns er pairs wv*2+j (j<2), all 8 tokens
        {
            float zacc[2][T8] = {};
            const float4* bp4[2];
            #pragma unroll
            for (int j = 0; j < 2; ++j) {
                int er = wv * 2 + j;
                int e = er >> 2, r = er & 3;
                bp4[j] = (const float4*)(expert_B + (size_t)((e * LL + li) * RR + r) * HD);
            }
            for (int k4 = 0; k4 < HD / 256; ++k4) {
                int idx = lane + k4 * 64;
                float4 hv[T8];
                #pragma unroll
                for (int t = 0; t < T8; ++t) hv[t] = ((const float4*)h_lds[t])[idx];
                #pragma unroll
                for (int j = 0; j < 2; ++j) {
                    float4 w4 = bp4[j][idx];
                    #pragma unroll
                    for (int t = 0; t < T8; ++t)
                        zacc[j][t] += w4.x * hv[t].x + w4.y * hv[t].y +
                                      w4.z * hv[t].z + w4.w * hv[t].w;
                }
            }
            #pragma unroll
            for (int j = 0; j < 2; ++j)
                #pragma unroll
                for (int t = 0; t < T8; ++t) {
                    float v = zacc[j][t];
                    for (int m = 1; m < 64; m <<= 1) v += __shfl_xor(v, m);
                    zacc[j][t] = v;
                }
            if (lane == 0) {
                #pragma unroll
                for (int j = 0; j < 2; ++j) {
                    int er = wv * 2 + j;
                    #pragma unroll
                    for (int t = 0; t < T8; ++t)
                        zw_lds[t][er] = zacc[j][t] * probs_lds[t][er >> 2];
                }
            }
        }
        __syncthreads();
        CVT_CHUNK(1);

        // ---- delta phase: wave owns h-positions [wv*256, wv*256+256), 4/lane
        float dacc[T8][4] = {};
        const int pbase = wv * 256 + lane;
        for (int e = 0; e < EE; ++e) {
            float zwt[T8][4];
            #pragma unroll
            for (int t = 0; t < T8; ++t)
                #pragma unroll
                for (int r = 0; r < RR; ++r) zwt[t][r] = zw_lds[t][e * 4 + r];
            const float4* ap = (const float4*)expert_A + (size_t)(e * LL + li) * HD;
            #pragma unroll
            for (int it = 0; it < 4; ++it) {
                float4 a4 = ap[pbase + it * 64];
                #pragma unroll
                for (int t = 0; t < T8; ++t)
                    dacc[t][it] += zwt[t][0] * a4.x + zwt[t][1] * a4.y +
                                   zwt[t][2] * a4.z + zwt[t][3] * a4.w;
            }
        }

        // ---- combined = h*psum + delta; deep-B low partials
        float lowacc[T8][4] = {};
        float psv[T8];
        #pragma unroll
        for (int t = 0; t < T8; ++t) psv[t] = psum_lds[t];
        const float* dbp = deep_B + (size_t)li * (RR * HD);
        #pragma unroll
        for (int it = 0; it < 4; ++it) {
            int pos = pbase + it * 64;
            float db0 = dbp[pos], db1 = dbp[HD + pos], db2 = dbp[2 * HD + pos], db3 = dbp[3 * HD + pos];
            #pragma unroll
            for (int t = 0; t < T8; ++t) {
                float c = h_lds[t][pos] * psv[t] + dacc[t][it];
                h_lds[t][pos] = c;
                lowacc[t][0] += c * db0; lowacc[t][1] += c * db1;
                lowacc[t][2] += c * db2; lowacc[t][3] += c * db3;
            }
        }
        #pragma unroll
        for (int t = 0; t < T8; ++t)
            #pragma unroll
            for (int r = 0; r < RR; ++r) {
                float v = lowacc[t][r];
                for (int m = 1; m < 64; m <<= 1) v += __shfl_xor(v, m);
                lowacc[t][r] = v;
            }
        if (lane == 0) {
            #pragma unroll
            for (int t = 0; t < T8; ++t)
                #pragma unroll
                for (int r = 0; r < RR; ++r) red[wv][t][r] = lowacc[t][r];
        }
        __syncthreads();
        if (tid < 32) {
            int t = tid >> 2, r = tid & 3;
            float s = 0.f;
            #pragma unroll
            for (int w = 0; w < 16; ++w) s += red[w][t][r];
            low_lds[t][r] = s;
        }
        __syncthreads();
        CVT_CHUNK(2);

        // ---- up phase: h += low @ deep_A^T
        {
            float lw[T8][4];
            #pragma unroll
            for (int t = 0; t < T8; ++t)
                #pragma unroll
                for (int r = 0; r < RR; ++r) lw[t][r] = low_lds[t][r];
            const float4* dap = (const float4*)deep_A + (size_t)li * HD;
            #pragma unroll
            for (int it = 0; it < 4; ++it) {
                int pos = pbase + it * 64;
                float4 a4 = dap[pos];
                #pragma unroll
                for (int t = 0; t < T8; ++t)
                    h_lds[t][pos] += lw[t][0] * a4.x + lw[t][1] * a4.y +
                                     lw[t][2] * a4.z + lw[t][3] * a4.w;
            }
        }
        __syncthreads();
        CVT_CHUNK(3);
    }

    // ---- epilogue: h -> bf16
    for (int t = 0; t < T8; ++t) {
        float4 v = ((const float4*)h_lds[t])[tid];
        ushort4 o;
        o.x = f2bf(v.x); o.y = f2bf(v.y); o.z = f2bf(v.z); o.w = f2bf(v.w);
        ((ushort4*)(h_out + (size_t)(t0 + t) * HD))[tid] = o;
    }
}

// ---------------------------------------------------------------------------
// Kernel 2: 256x256 8-phase bf16 GEMM — R4/R8-EXACT (known 518 us; R9's
// deep-prefetch regressed to 595: stage bursts in P3 beat the per-phase
// spread. Do not touch.)
// Phase read balance: P0: 8 A | P1: 4 B | P2: 8 A | P3: 4 B(next, post-vmcnt).
// vmcnt ledger at P3: outstanding = B(kt+1):4 + A(kt+1):4 + B(kt+2):4 = 12;
// vmcnt(4) drains tile kt+1, leaves B(kt+2) in flight.
// ---------------------------------------------------------------------------
#define GLD(src, dst) __builtin_amdgcn_global_load_lds( \
    (const __attribute__((address_space(1))) unsigned int*)(src), \
    (__attribute__((address_space(3))) unsigned int*)(dst), 16, 0, 0)

#define STAGE(pp, matoff, bufv, hh, ktv) do { \
    char* db_ = smem + (bufv) * 65536 + (matoff) + (hh) * 16384 + wv * 1024; \
    GLD(pp[0] + (size_t)(hh) * (128ull * HD * 2) + (size_t)(ktv) * 128, db_); \
    GLD(pp[1] + (size_t)(hh) * (128ull * HD * 2) + (size_t)(ktv) * 128, db_ + 8192); \
} while (0)

#define LDSREAD(off) (*(const bf16x8*)(smem + (off)))

__global__ __launch_bounds__(512, 2) void lm_gemm256(
    const unsigned short* __restrict__ A,
    const unsigned short* __restrict__ Bw,
    float* __restrict__ C)
{
    __shared__ __attribute__((aligned(128))) char smem[131072];

    const int bid = blockIdx.x;
    const int swz = (bid & 7) * 125 + (bid >> 3);
    const int bm = swz & 7;
    const int bn = swz >> 3;

    const int tid  = threadIdx.x;
    const int lane = tid & 63;
    const int wv   = tid >> 6;
    const int wr   = wv >> 2;
    const int wc   = wv & 3;

    const char* pA[2];
    const char* pB[2];
    #pragma unroll
    for (int q = 0; q < 2; ++q) {
        int off = (q * 512 + tid) * 16;
        int p = off ^ (((off >> 9) & 1) << 5);
        int st = p >> 10;
        int r  = (st >> 1) * 16 + ((p >> 6) & 15);
        int cb = (st & 1) * 64 + (p & 63);
        pA[q] = (const char*)(A  + (size_t)(bm * 256 + r) * HD) + cb;
        pB[q] = (const char*)(Bw + (size_t)(bn * 256 + r) * HD) + cb;
    }

    const int xlane = ((lane >> 3) & 1) << 5;
    const int abase = ((wr * 8) << 11) + ((lane & 15) << 6) + ((lane >> 4) << 4);
    const int bbase = 32768 + ((wc * 4) << 11) + ((lane & 15) << 6) + ((lane >> 4) << 4);

    f32x4 acc[8][4] = {};
    bf16x8 aF[4][2], bF0[2][2][2], bF1[2][2];

    STAGE(pB, 32768, 0, 0, 0);
    STAGE(pB, 32768, 0, 1, 0);
    STAGE(pA, 0,     0, 0, 0);
    STAGE(pA, 0,     0, 1, 0);
    STAGE(pB, 32768, 1, 0, 1);
    STAGE(pB, 32768, 1, 1, 1);
    asm volatile("s_waitcnt vmcnt(4)" ::: "memory");
    __builtin_amdgcn_s_barrier();
    __builtin_amdgcn_sched_barrier(0);
    #pragma unroll
    for (int n = 0; n < 2; ++n)
        #pragma unroll
        for (int ks = 0; ks < 2; ++ks)
            bF0[0][n][ks] = LDSREAD(((bbase + (n << 11) + (ks << 10)) ^ xlane));

    #pragma unroll 2
    for (int kt = 0; kt < NKT; ++kt) {
        const int cur = kt & 1;
        const int oth = cur ^ 1;
        const int cb0 = cur << 16;

        // ---------------- PHASE 0 : (mh0, nh0)  [8 A reads]
        #pragma unroll
        for (int i = 0; i < 4; ++i)
            #pragma unroll
            for (int ks = 0; ks < 2; ++ks)
                aF[i][ks] = LDSREAD(cb0 + ((abase + (i << 11) + (ks << 10)) ^ xlane));
        if (kt + 1 < NKT) STAGE(pA, 0, oth, 0, kt + 1);
        __builtin_amdgcn_s_barrier();
        __builtin_amdgcn_sched_barrier(0);
        __builtin_amdgcn_s_setprio(1);
        #pragma unroll
        for (int ks = 0; ks < 2; ++ks)
            #pragma unroll
            for (int i = 0; i < 4; ++i)
                #pragma unroll
                for (int n = 0; n < 2; ++n)
                    acc[i][n] = __builtin_amdgcn_mfma_f32_16x16x32_bf16(
                        aF[i][ks], bF0[cur][n][ks], acc[i][n], 0, 0, 0);
        __builtin_amdgcn_s_setprio(0);
        __builtin_amdgcn_s_barrier();
        __builtin_amdgcn_sched_barrier(0);

        // ---------------- PHASE 1 : (mh0, nh1)  [4 B reads]
        #pragma unroll
        for (int n = 0; n < 2; ++n)
            #pragma unroll
            for (int ks = 0; ks < 2; ++ks)
                bF1[n][ks] = LDSREAD(cb0 + ((bbase + ((n + 2) << 11) + (ks << 10)) ^ xlane));
        if (kt + 1 < NKT) STAGE(pA, 0, oth, 1, kt + 1);
        __builtin_amdgcn_s_barrier();
        __builtin_amdgcn_sched_barrier(0);
        __builtin_amdgcn_s_setprio(1);
        #pragma unroll
        for (int ks = 0; ks < 2; ++ks)
            #pragma unroll
            for (int i = 0; i < 4; ++i)
                #pragma unroll
                for (int n = 0; n < 2; ++n)
                    acc[i][n + 2] = __builtin_amdgcn_mfma_f32_16x16x32_bf16(
                        aF[i][ks], bF1[n][ks], acc[i][n + 2], 0, 0, 0);
        __builtin_amdgcn_s_setprio(0);
        __builtin_amdgcn_s_barrier();
        __builtin_amdgcn_sched_barrier(0);

        // ---------------- PHASE 2 : (mh1, nh1)  [8 A reads]
        #pragma unroll
        for (int i = 0; i < 4; ++i)
            #pragma unroll
            for (int ks = 0; ks < 2; ++ks)
                aF[i][ks] = LDSREAD(cb0 + ((abase + ((i + 4) << 11) + (ks << 10)) ^ xlane));
        if (kt + 2 < NKT) STAGE(pB, 32768, cur, 0, kt + 2);
        __builtin_amdgcn_s_barrier();
        __builtin_amdgcn_sched_barrier(0);
        __builtin_amdgcn_s_setprio(1);
        #pragma unroll
        for (int ks = 0; ks < 2; ++ks)
            #pragma unroll
            for (int i = 0; i < 4; ++i)
                #pragma unroll
                for (int n = 0; n < 2; ++n)
                    acc[i + 4][n + 2] = __builtin_amdgcn_mfma_f32_16x16x32_bf16(
                        aF[i][ks], bF1[n][ks], acc[i + 4][n + 2], 0, 0, 0);
        __builtin_amdgcn_s_setprio(0);
        __builtin_amdgcn_s_barrier();
        __builtin_amdgcn_sched_barrier(0);

        // ---------------- PHASE 3 : (mh1, nh0)  [4 B(next) reads after barrier]
        if (kt + 2 < NKT) {
            STAGE(pB, 32768, cur, 1, kt + 2);
            asm volatile("s_waitcnt vmcnt(4)" ::: "memory");
        } else {
            asm volatile("s_waitcnt vmcnt(0)" ::: "memory");
        }
        __builtin_amdgcn_s_barrier();
        __builtin_amdgcn_sched_barrier(0);
        if (kt + 1 < NKT) {
            const int nb0 = oth << 16;
            #pragma unroll
            for (int n = 0; n < 2; ++n)
                #pragma unroll
                for (int ks = 0; ks < 2; ++ks)
                    bF0[oth][n][ks] = LDSREAD(nb0 + ((bbase + (n << 11) + (ks << 10)) ^ xlane));
        }
        __builtin_amdgcn_s_setprio(1);
        #pragma unroll
        for (int ks = 0; ks < 2; ++ks)
            #pragma unroll
            for (int i = 0; i < 4; ++i)
                #pragma unroll
                for (int n = 0; n < 2; ++n)
                    acc[i + 4][n] = __builtin_amdgcn_mfma_f32_16x16x32_bf16(
                        aF[i][ks], bF0[cur][n][ks], acc[i + 4][n], 0, 0, 0);
        __builtin_amdgcn_s_setprio(0);
        __builtin_amdgcn_s_barrier();
        __builtin_amdgcn_sched_barrier(0);
    }

    const int crow0 = bm * 256 + wr * 128 + ((lane >> 4) << 2);
    const int ccol0 = bn * 256 + wc * 64 + (lane & 15);
    #pragma unroll
    for (int fm = 0; fm < 8; ++fm)
        #pragma unroll
        for (int fn = 0; fn < 4; ++fn) {
            int row = crow0 + fm * 16;
            int col = ccol0 + fn * 16;
            #pragma unroll
            for (int j = 0; j < 4; ++j)
                C[(size_t)(row + j) * VV + col] = acc[fm][fn][j];
        }
}

// ---------------------------------------------------------------------------
extern "C" void kernel_launch(void* const* d_in, const int* in_sizes, int n_in,
                              void* d_out, int out_size, void* d_ws, size_t ws_size,
                              hipStream_t stream) {
    const float* h_in      = (const float*)d_in[0];
    const float* router_w  = (const float*)d_in[1];
    const float* router_b  = (const float*)d_in[2];
    const float* expert_B  = (const float*)d_in[3];
    const float* expert_A  = (const float*)d_in[4];
    const float* deep_B    = (const float*)d_in[5];
    const float* deep_A    = (const float*)d_in[6];
    const float* lm_head_w = (const float*)d_in[7];

    float* out = (float*)d_out;
    float* router_logits_out = out + (size_t)NTOK * VV;

    unsigned short* h_bf = (unsigned short*)d_ws;
    unsigned short* w_bf = (unsigned short*)((char*)d_ws + (size_t)NTOK * HD * 2);

    fused_layers_cvt<<<dim3(NTOK / T8), dim3(1024), 0, stream>>>(
        h_in, router_w, router_b, expert_B, expert_A, deep_B, deep_A,
        router_logits_out, h_bf, (const f32x4*)lm_head_w, (u16x4*)w_bf);

    lm_gemm256<<<dim3((NTOK / 256) * (VV / 256)), dim3(512), 0, stream>>>(
        h_bf, w_bf, out);
}

// Round 11
// 902.751 us; speedup vs baseline: 1.0844x; 1.0000x over previous
//
#include <hip/hip_runtime.h>
#include <cstdint>
#include <cstddef>

#define HD 4096
#define EE 8
#define LL 8
#define RR 4
#define VV 32000
#define NTOK 2048
#define NKT (HD / 64)   // 64 K-tiles of BK=64
#define T8 8            // tokens per layer block
#define N4 (VV * HD / 4)  // 32,768,000 float4 elements in lm_head_w

typedef __attribute__((ext_vector_type(8))) short bf16x8;
typedef __attribute__((ext_vector_type(4))) float f32x4;
typedef __attribute__((ext_vector_type(4))) unsigned short u16x4;

static __device__ __forceinline__ unsigned short f2bf(float f) {
    unsigned int u = __builtin_bit_cast(unsigned int, f);
    unsigned int r = (u + 0x7FFFu + ((u >> 16) & 1u)) >> 16;
    return (unsigned short)r;
}

// Raw barrier: LDS-only ordering (lgkmcnt), NO vmcnt drain. This keeps the
// inline nontemporal cvt stores (which only feed the LATER gemm kernel via
// w_bf) out of the barrier critical path — __syncthreads' vmcnt(0) drain was
// serializing every cvt HBM round-trip into the layer phase chain (R10 null
// overlap). Layer global weight loads are register-consumed => compiler
// auto-waits before use; LDS producers/consumers ordered by lgkmcnt(0).
#define BAR() do { \
    asm volatile("s_waitcnt lgkmcnt(0)" ::: "memory"); \
    __builtin_amdgcn_s_barrier(); \
    __builtin_amdgcn_sched_barrier(0); \
} while (0)

// ---------------------------------------------------------------------------
// Kernel 1: router + 8 LoRA layers + inline lm_head_w cvt (thread-granular,
// nontemporal, now truly async thanks to BAR()).
// 256 blocks x 1024 threads (16 waves); 8 tokens/block; runs ALONE.
// ---------------------------------------------------------------------------
#define CVT_CHUNK(c) do { \
    size_t base_ = ((size_t)(li * 4 + (c)) * 256 + blockIdx.x) * 4096; \
    _Pragma("unroll") \
    for (int q_ = 0; q_ < 4; ++q_) { \
        size_t i_ = base_ + q_ * 1024 + tid; \
        if (i_ < (size_t)N4) { \
            f32x4 v_ = __builtin_nontemporal_load(&lm_w[i_]); \
            u16x4 o_; \
            o_.x = f2bf(v_.x); o_.y = f2bf(v_.y); \
            o_.z = f2bf(v_.z); o_.w = f2bf(v_.w); \
            __builtin_nontemporal_store(o_, &w_bf[i_]); \
        } \
    } \
} while (0)

__global__ __launch_bounds__(1024, 4) void fused_layers_cvt(
    const float* __restrict__ h_in,
    const float* __restrict__ router_w,
    const float* __restrict__ router_b,
    const float* __restrict__ expert_B,   // [E][L][R][H]
    const float* __restrict__ expert_A,   // [E][L][H][R]
    const float* __restrict__ deep_B,     // [L][R][H]
    const float* __restrict__ deep_A,     // [L][H][R]
    float* __restrict__ router_logits,
    unsigned short* __restrict__ h_out,
    const f32x4* __restrict__ lm_w,
    u16x4* __restrict__ w_bf)
{
    __shared__ float h_lds[T8][HD];       // 128 KB
    __shared__ float zw_lds[T8][32];
    __shared__ float probs_lds[T8][EE];
    __shared__ float psum_lds[T8];
    __shared__ float red[16][T8][4];
    __shared__ float low_lds[T8][4];

    const int tid  = threadIdx.x;
    const int lane = tid & 63;
    const int wv   = tid >> 6;            // 0..15
    const int t0   = blockIdx.x * T8;

    for (int t = 0; t < T8; ++t)
        ((float4*)h_lds[t])[tid] = ((const float4*)(h_in + (size_t)(t0 + t) * HD))[tid];
    BAR();

    if (wv < T8) {
        float racc[EE];
        #pragma unroll
        for (int e = 0; e < EE; ++e) racc[e] = 0.f;
        const float4* h4 = (const float4*)h_lds[wv];
        for (int k4 = 0; k4 < HD / 256; ++k4) {
            int idx = lane + k4 * 64;
            float4 hv = h4[idx];
            #pragma unroll
            for (int e = 0; e < EE; ++e) {
                float4 w4 = ((const float4*)(router_w + e * HD))[idx];
                racc[e] += w4.x * hv.x + w4.y * hv.y + w4.z * hv.z + w4.w * hv.w;
            }
        }
        #pragma unroll
        for (int e = 0; e < EE; ++e)
            for (int m = 1; m < 64; m <<= 1) racc[e] += __shfl_xor(racc[e], m);
        if (lane == 0) {
            float lg[EE], mx = -1e30f;
            #pragma unroll
            for (int e = 0; e < EE; ++e) { lg[e] = racc[e] + router_b[e]; mx = fmaxf(mx, lg[e]); }
            float s = 0.f;
            #pragma unroll
            for (int e = 0; e < EE; ++e) { lg[e] = expf(lg[e] - mx); s += lg[e]; }
            float inv = 1.f / s;
            float p1[EE], mx2 = -1e30f;
            #pragma unroll
            for (int e = 0; e < EE; ++e) { p1[e] = lg[e] * inv; mx2 = fmaxf(mx2, p1[e]); }
            float s2 = 0.f, q2[EE];
            #pragma unroll
            for (int e = 0; e < EE; ++e) { q2[e] = expf(p1[e] - mx2); s2 += q2[e]; }
            float inv2 = 1.f / s2, ps = 0.f;
            #pragma unroll
            for (int e = 0; e < EE; ++e) {
                float p2 = q2[e] * inv2;
                probs_lds[wv][e] = p2;
                ps += p2;
                router_logits[(size_t)(t0 + wv) * EE + e] = p1[e];
            }
            psum_lds[wv] = ps;
        }
    }
    BAR();

    for (int li = 0; li < LL; ++li) {
        CVT_CHUNK(0);
        // ---- Z phase: wave wv owns er pairs wv*2+j (j<2), all 8 tokens
        {
            float zacc[2][T8] = {};
            const float4* bp4[2];
            #pragma unroll
            for (int j = 0; j < 2; ++j) {
                int er = wv * 2 + j;
                int e = er >> 2, r = er & 3;
                bp4[j] = (const float4*)(expert_B + (size_t)((e * LL + li) * RR + r) * HD);
            }
            for (int k4 = 0; k4 < HD / 256; ++k4) {
                int idx = lane + k4 * 64;
                float4 hv[T8];
                #pragma unroll
                for (int t = 0; t < T8; ++t) hv[t] = ((const float4*)h_lds[t])[idx];
                #pragma unroll
                for (int j = 0; j < 2; ++j) {
                    float4 w4 = bp4[j][idx];
                    #pragma unroll
                    for (int t = 0; t < T8; ++t)
                        zacc[j][t] += w4.x * hv[t].x + w4.y * hv[t].y +
                                      w4.z * hv[t].z + w4.w * hv[t].w;
                }
            }
            #pragma unroll
            for (int j = 0; j < 2; ++j)
                #pragma unroll
                for (int t = 0; t < T8; ++t) {
                    float v = zacc[j][t];
                    for (int m = 1; m < 64; m <<= 1) v += __shfl_xor(v, m);
                    zacc[j][t] = v;
                }
            if (lane == 0) {
                #pragma unroll
                for (int j = 0; j < 2; ++j) {
                    int er = wv * 2 + j;
                    #pragma unroll
                    for (int t = 0; t < T8; ++t)
                        zw_lds[t][er] = zacc[j][t] * probs_lds[t][er >> 2];
                }
            }
        }
        BAR();
        CVT_CHUNK(1);

        // ---- delta phase: wave owns h-positions [wv*256, wv*256+256), 4/lane
        float dacc[T8][4] = {};
        const int pbase = wv * 256 + lane;
        for (int e = 0; e < EE; ++e) {
            float zwt[T8][4];
            #pragma unroll
            for (int t = 0; t < T8; ++t)
                #pragma unroll
                for (int r = 0; r < RR; ++r) zwt[t][r] = zw_lds[t][e * 4 + r];
            const float4* ap = (const float4*)expert_A + (size_t)(e * LL + li) * HD;
            #pragma unroll
            for (int it = 0; it < 4; ++it) {
                float4 a4 = ap[pbase + it * 64];
                #pragma unroll
                for (int t = 0; t < T8; ++t)
                    dacc[t][it] += zwt[t][0] * a4.x + zwt[t][1] * a4.y +
                                   zwt[t][2] * a4.z + zwt[t][3] * a4.w;
            }
        }

        // ---- combined = h*psum + delta; deep-B low partials
        float lowacc[T8][4] = {};
        float psv[T8];
        #pragma unroll
        for (int t = 0; t < T8; ++t) psv[t] = psum_lds[t];
        const float* dbp = deep_B + (size_t)li * (RR * HD);
        #pragma unroll
        for (int it = 0; it < 4; ++it) {
            int pos = pbase + it * 64;
            float db0 = dbp[pos], db1 = dbp[HD + pos], db2 = dbp[2 * HD + pos], db3 = dbp[3 * HD + pos];
            #pragma unroll
            for (int t = 0; t < T8; ++t) {
                float c = h_lds[t][pos] * psv[t] + dacc[t][it];
                h_lds[t][pos] = c;
                lowacc[t][0] += c * db0; lowacc[t][1] += c * db1;
                lowacc[t][2] += c * db2; lowacc[t][3] += c * db3;
            }
        }
        #pragma unroll
        for (int t = 0; t < T8; ++t)
            #pragma unroll
            for (int r = 0; r < RR; ++r) {
                float v = lowacc[t][r];
                for (int m = 1; m < 64; m <<= 1) v += __shfl_xor(v, m);
                lowacc[t][r] = v;
            }
        if (lane == 0) {
            #pragma unroll
            for (int t = 0; t < T8; ++t)
                #pragma unroll
                for (int r = 0; r < RR; ++r) red[wv][t][r] = lowacc[t][r];
        }
        BAR();
        if (tid < 32) {
            int t = tid >> 2, r = tid & 3;
            float s = 0.f;
            #pragma unroll
            for (int w = 0; w < 16; ++w) s += red[w][t][r];
            low_lds[t][r] = s;
        }
        BAR();
        CVT_CHUNK(2);

        // ---- up phase: h += low @ deep_A^T
        {
            float lw[T8][4];
            #pragma unroll
            for (int t = 0; t < T8; ++t)
                #pragma unroll
                for (int r = 0; r < RR; ++r) lw[t][r] = low_lds[t][r];
            const float4* dap = (const float4*)deep_A + (size_t)li * HD;
            #pragma unroll
            for (int it = 0; it < 4; ++it) {
                int pos = pbase + it * 64;
                float4 a4 = dap[pos];
                #pragma unroll
                for (int t = 0; t < T8; ++t)
                    h_lds[t][pos] += lw[t][0] * a4.x + lw[t][1] * a4.y +
                                     lw[t][2] * a4.z + lw[t][3] * a4.w;
            }
        }
        BAR();
        CVT_CHUNK(3);
    }

    // ---- epilogue: h -> bf16 (kernel end drains all stores implicitly)
    for (int t = 0; t < T8; ++t) {
        float4 v = ((const float4*)h_lds[t])[tid];
        ushort4 o;
        o.x = f2bf(v.x); o.y = f2bf(v.y); o.z = f2bf(v.z); o.w = f2bf(v.w);
        ((ushort4*)(h_out + (size_t)(t0 + t) * HD))[tid] = o;
    }
}

// ---------------------------------------------------------------------------
// Kernel 2: 256x256 8-phase bf16 GEMM — R4/R8-EXACT (518 us plateau for this
// shape; 4 schedule perturbations all <= it. Do not touch.)
// Phase read balance: P0: 8 A | P1: 4 B | P2: 8 A | P3: 4 B(next, post-vmcnt).
// vmcnt ledger at P3: outstanding = B(kt+1):4 + A(kt+1):4 + B(kt+2):4 = 12;
// vmcnt(4) drains tile kt+1, leaves B(kt+2) in flight.
// ---------------------------------------------------------------------------
#define GLD(src, dst) __builtin_amdgcn_global_load_lds( \
    (const __attribute__((address_space(1))) unsigned int*)(src), \
    (__attribute__((address_space(3))) unsigned int*)(dst), 16, 0, 0)

#define STAGE(pp, matoff, bufv, hh, ktv) do { \
    char* db_ = smem + (bufv) * 65536 + (matoff) + (hh) * 16384 + wv * 1024; \
    GLD(pp[0] + (size_t)(hh) * (128ull * HD * 2) + (size_t)(ktv) * 128, db_); \
    GLD(pp[1] + (size_t)(hh) * (128ull * HD * 2) + (size_t)(ktv) * 128, db_ + 8192); \
} while (0)

#define LDSREAD(off) (*(const bf16x8*)(smem + (off)))

__global__ __launch_bounds__(512, 2) void lm_gemm256(
    const unsigned short* __restrict__ A,
    const unsigned short* __restrict__ Bw,
    float* __restrict__ C)
{
    __shared__ __attribute__((aligned(128))) char smem[131072];

    const int bid = blockIdx.x;
    const int swz = (bid & 7) * 125 + (bid >> 3);
    const int bm = swz & 7;
    const int bn = swz >> 3;

    const int tid  = threadIdx.x;
    const int lane = tid & 63;
    const int wv   = tid >> 6;
    const int wr   = wv >> 2;
    const int wc   = wv & 3;

    const char* pA[2];
    const char* pB[2];
    #pragma unroll
    for (int q = 0; q < 2; ++q) {
        int off = (q * 512 + tid) * 16;
        int p = off ^ (((off >> 9) & 1) << 5);
        int st = p >> 10;
        int r  = (st >> 1) * 16 + ((p >> 6) & 15);
        int cb = (st & 1) * 64 + (p & 63);
        pA[q] = (const char*)(A  + (size_t)(bm * 256 + r) * HD) + cb;
        pB[q] = (const char*)(Bw + (size_t)(bn * 256 + r) * HD) + cb;
    }

    const int xlane = ((lane >> 3) & 1) << 5;
    const int abase = ((wr * 8) << 11) + ((lane & 15) << 6) + ((lane >> 4) << 4);
    const int bbase = 32768 + ((wc * 4) << 11) + ((lane & 15) << 6) + ((lane >> 4) << 4);

    f32x4 acc[8][4] = {};
    bf16x8 aF[4][2], bF0[2][2][2], bF1[2][2];

    STAGE(pB, 32768, 0, 0, 0);
    STAGE(pB, 32768, 0, 1, 0);
    STAGE(pA, 0,     0, 0, 0);
    STAGE(pA, 0,     0, 1, 0);
    STAGE(pB, 32768, 1, 0, 1);
    STAGE(pB, 32768, 1, 1, 1);
    asm volatile("s_waitcnt vmcnt(4)" ::: "memory");
    __builtin_amdgcn_s_barrier();
    __builtin_amdgcn_sched_barrier(0);
    #pragma unroll
    for (int n = 0; n < 2; ++n)
        #pragma unroll
        for (int ks = 0; ks < 2; ++ks)
            bF0[0][n][ks] = LDSREAD(((bbase + (n << 11) + (ks << 10)) ^ xlane));

    #pragma unroll 2
    for (int kt = 0; kt < NKT; ++kt) {
        const int cur = kt & 1;
        const int oth = cur ^ 1;
        const int cb0 = cur << 16;

        // ---------------- PHASE 0 : (mh0, nh0)  [8 A reads]
        #pragma unroll
        for (int i = 0; i < 4; ++i)
            #pragma unroll
            for (int ks = 0; ks < 2; ++ks)
                aF[i][ks] = LDSREAD(cb0 + ((abase + (i << 11) + (ks << 10)) ^ xlane));
        if (kt + 1 < NKT) STAGE(pA, 0, oth, 0, kt + 1);
        __builtin_amdgcn_s_barrier();
        __builtin_amdgcn_sched_barrier(0);
        __builtin_amdgcn_s_setprio(1);
        #pragma unroll
        for (int ks = 0; ks < 2; ++ks)
            #pragma unroll
            for (int i = 0; i < 4; ++i)
                #pragma unroll
                for (int n = 0; n < 2; ++n)
                    acc[i][n] = __builtin_amdgcn_mfma_f32_16x16x32_bf16(
                        aF[i][ks], bF0[cur][n][ks], acc[i][n], 0, 0, 0);
        __builtin_amdgcn_s_setprio(0);
        __builtin_amdgcn_s_barrier();
        __builtin_amdgcn_sched_barrier(0);

        // ---------------- PHASE 1 : (mh0, nh1)  [4 B reads]
        #pragma unroll
        for (int n = 0; n < 2; ++n)
            #pragma unroll
            for (int ks = 0; ks < 2; ++ks)
                bF1[n][ks] = LDSREAD(cb0 + ((bbase + ((n + 2) << 11) + (ks << 10)) ^ xlane));
        if (kt + 1 < NKT) STAGE(pA, 0, oth, 1, kt + 1);
        __builtin_amdgcn_s_barrier();
        __builtin_amdgcn_sched_barrier(0);
        __builtin_amdgcn_s_setprio(1);
        #pragma unroll
        for (int ks = 0; ks < 2; ++ks)
            #pragma unroll
            for (int i = 0; i < 4; ++i)
                #pragma unroll
                for (int n = 0; n < 2; ++n)
                    acc[i][n + 2] = __builtin_amdgcn_mfma_f32_16x16x32_bf16(
                        aF[i][ks], bF1[n][ks], acc[i][n + 2], 0, 0, 0);
        __builtin_amdgcn_s_setprio(0);
        __builtin_amdgcn_s_barrier();
        __builtin_amdgcn_sched_barrier(0);

        // ---------------- PHASE 2 : (mh1, nh1)  [8 A reads]
        #pragma unroll
        for (int i = 0; i < 4; ++i)
            #pragma unroll
            for (int ks = 0; ks < 2; ++ks)
                aF[i][ks] = LDSREAD(cb0 + ((abase + ((i + 4) << 11) + (ks << 10)) ^ xlane));
        if (kt + 2 < NKT) STAGE(pB, 32768, cur, 0, kt + 2);
        __builtin_amdgcn_s_barrier();
        __builtin_amdgcn_sched_barrier(0);
        __builtin_amdgcn_s_setprio(1);
        #pragma unroll
        for (int ks = 0; ks < 2; ++ks)
            #pragma unroll
            for (int i = 0; i < 4; ++i)
                #pragma unroll
                for (int n = 0; n < 2; ++n)
                    acc[i + 4][n + 2] = __builtin_amdgcn_mfma_f32_16x16x32_bf16(
                        aF[i][ks], bF1[n][ks], acc[i + 4][n + 2], 0, 0, 0);
        __builtin_amdgcn_s_setprio(0);
        __builtin_amdgcn_s_barrier();
        __builtin_amdgcn_sched_barrier(0);

        // ---------------- PHASE 3 : (mh1, nh0)  [4 B(next) reads after barrier]
        if (kt + 2 < NKT) {
            STAGE(pB, 32768, cur, 1, kt + 2);
            asm volatile("s_waitcnt vmcnt(4)" ::: "memory");
        } else {
            asm volatile("s_waitcnt vmcnt(0)" ::: "memory");
        }
        __builtin_amdgcn_s_barrier();
        __builtin_amdgcn_sched_barrier(0);
        if (kt + 1 < NKT) {
            const int nb0 = oth << 16;
            #pragma unroll
            for (int n = 0; n < 2; ++n)
                #pragma unroll
                for (int ks = 0; ks < 2; ++ks)
                    bF0[oth][n][ks] = LDSREAD(nb0 + ((bbase + (n << 11) + (ks << 10)) ^ xlane));
        }
        __builtin_amdgcn_s_setprio(1);
        #pragma unroll
        for (int ks = 0; ks < 2; ++ks)
            #pragma unroll
            for (int i = 0; i < 4; ++i)
                #pragma unroll
                for (int n = 0; n < 2; ++n)
                    acc[i + 4][n] = __builtin_amdgcn_mfma_f32_16x16x32_bf16(
                        aF[i][ks], bF0[cur][n][ks], acc[i + 4][n], 0, 0, 0);
        __builtin_amdgcn_s_setprio(0);
        __builtin_amdgcn_s_barrier();
        __builtin_amdgcn_sched_barrier(0);
    }

    const int crow0 = bm * 256 + wr * 128 + ((lane >> 4) << 2);
    const int ccol0 = bn * 256 + wc * 64 + (lane & 15);
    #pragma unroll
    for (int fm = 0; fm < 8; ++fm)
        #pragma unroll
        for (int fn = 0; fn < 4; ++fn) {
            int row = crow0 + fm * 16;
            int col = ccol0 + fn * 16;
            #pragma unroll
            for (int j = 0; j < 4; ++j)
                C[(size_t)(row + j) * VV + col] = acc[fm][fn][j];
        }
}

// ---------------------------------------------------------------------------
extern "C" void kernel_launch(void* const* d_in, const int* in_sizes, int n_in,
                              void* d_out, int out_size, void* d_ws, size_t ws_size,
                              hipStream_t stream) {
    const float* h_in      = (const float*)d_in[0];
    const float* router_w  = (const float*)d_in[1];
    const float* router_b  = (const float*)d_in[2];
    const float* expert_B  = (const float*)d_in[3];
    const float* expert_A  = (const float*)d_in[4];
    const float* deep_B    = (const float*)d_in[5];
    const float* deep_A    = (const float*)d_in[6];
    const float* lm_head_w = (const float*)d_in[7];

    float* out = (float*)d_out;
    float* router_logits_out = out + (size_t)NTOK * VV;

    unsigned short* h_bf = (unsigned short*)d_ws;
    unsigned short* w_bf = (unsigned short*)((char*)d_ws + (size_t)NTOK * HD * 2);

    fused_layers_cvt<<<dim3(NTOK / T8), dim3(1024), 0, stream>>>(
        h_in, router_w, router_b, expert_B, expert_A, deep_B, deep_A,
        router_logits_out, h_bf, (const f32x4*)lm_head_w, (u16x4*)w_bf);

    lm_gemm256<<<dim3((NTOK / 256) * (VV / 256)), dim3(512), 0, stream>>>(
        h_bf, w_bf, out);
}